// Round 8
// baseline (4142.136 us; speedup 1.0000x reference)
//
#include <hip/hip_runtime.h>

#define BB 128
#define TT 1024
#define II 100
#define HH 200
#define MB 16          // batches per recurrence block -> 8 blocks
#define NTL 13         // ceil(200/16) j-tiles
#define KST 7          // ceil(200/32) k-steps
#define HSTR 232       // padded f16 row stride for H_lds (16B-aligned rows)

typedef _Float16 half8  __attribute__((ext_vector_type(8)));
typedef _Float16 half4v __attribute__((ext_vector_type(4)));
typedef float    f32x4  __attribute__((ext_vector_type(4)));

// ---------------------------------------------------------------------------
// Phase 1: xp[r][j] = b_ih[j] + b_hh[j] + sum_i x[r][i] * W_ih[j][i]
// Destination parameterized: d_ws (fast path) or hid (fallback).
// ---------------------------------------------------------------------------
__global__ __launch_bounds__(256, 1) void rnn_xproj(
    const float* __restrict__ x, const float* __restrict__ Wih,
    const float* __restrict__ bih, const float* __restrict__ bhh,
    float* __restrict__ xpdst)
{
    __shared__ __align__(16) float xs[128 * II];  // 51.2 KB
    const int tid = threadIdx.x;
    const int j = tid;
    const int jl = (j < HH) ? j : (HH - 1);

    float4 w[25];
    const float4* wrow = (const float4*)(Wih + jl * II);
#pragma unroll
    for (int kk = 0; kk < 25; ++kk) w[kk] = wrow[kk];
    const float bias = bih[jl] + bhh[jl];

    const long long r0 = (long long)blockIdx.x * 128;
    const float4* src = (const float4*)(x + r0 * II);
    float4* dst = (float4*)xs;
    for (int p = tid; p < 128 * II / 4; p += 256) dst[p] = src[p];
    __syncthreads();

    for (int row = 0; row < 128; ++row) {
        float a0 = 0.f, a1 = 0.f, a2 = 0.f, a3 = 0.f;
        const float4* xr = (const float4*)(xs + row * II);
#pragma unroll
        for (int kk = 0; kk < 25; ++kk) {
            float4 v = xr[kk];
            a0 += w[kk].x * v.x; a1 += w[kk].y * v.y;
            a2 += w[kk].z * v.z; a3 += w[kk].w * v.w;
        }
        if (j < HH)
            xpdst[(r0 + row) * HH + j] = bias + ((a0 + a1) + (a2 + a3));
    }
}

// ---------------------------------------------------------------------------
// Phase 2: single-wave MFMA recurrence. 8 blocks x 64 threads (ONE wave).
// The wave computes the full 200x200 update for 16 batches: 13 j-tiles x
// 7 k-steps = 91 mfma_f32_16x16x32_f16 per step (~441 cyc issue floor).
// NO barriers: h exchange is in-wave through LDS, ordered by lgkmcnt which
// the compiler inserts. W_hh in 364 VGPRs (waves_per_eu(1,1) -> 512 budget).
// WS variant: xp stream in d_ws, h stream in hid -> compiler-visible
// NoAlias -> h stores never ordered against xp prefetch loads.
// Layouts (16x16x32, verified by r5 pass): A lane l: row=l&15, k=8*(l>>4)+e;
// B lane l: col=l&15, k=8*(l>>4)+e; C lane l: col=l&15, row=4*(l>>4)+r.
// ---------------------------------------------------------------------------
template <bool WS>
__global__ __launch_bounds__(64, 1) __attribute__((amdgpu_waves_per_eu(1, 1)))
void rnn_recur(const float* __restrict__ Whh, const float* xp, float* hid)
{
#if __has_builtin(__builtin_assume_separate_storage)
    if constexpr (WS) __builtin_assume_separate_storage((void*)xp, (void*)hid);
#endif
    __shared__ _Float16 hl[2][MB][HSTR];   // 14.8 KB double-buffered H (fp16)

    const int l  = threadIdx.x;   // 0..63
    const int m  = l & 15;        // batch (B-col / C-col)
    const int kq = l >> 4;        // k-subblock 0..3

    // ---- one-time: FULL W_hh -> A-fragments in registers (364 VGPR) ----
    half8 wf[NTL][KST];
#pragma unroll
    for (int nt = 0; nt < NTL; ++nt) {
        const int j = 16 * nt + m;
        const bool v = (j < HH);
        const int jl = v ? j : (HH - 1);
#pragma unroll
        for (int ks = 0; ks < KST; ++ks) {
            const int k0 = 32 * ks + 8 * kq;
            half8 f;
#pragma unroll
            for (int e = 0; e < 8; ++e) f[e] = (_Float16)0.f;
            if (v && k0 < HH) {   // k0 mult of 8, k0<=192 -> 8 floats in bounds
                const float4 lo = *(const float4*)(Whh + jl * HH + k0);
                const float4 hi = *(const float4*)(Whh + jl * HH + k0 + 4);
                f[0] = (_Float16)lo.x; f[1] = (_Float16)lo.y;
                f[2] = (_Float16)lo.z; f[3] = (_Float16)lo.w;
                f[4] = (_Float16)hi.x; f[5] = (_Float16)hi.y;
                f[6] = (_Float16)hi.z; f[7] = (_Float16)hi.w;
            }
            wf[nt][ks] = f;
        }
    }

    // zero both H buffers (incl. k-padding columns; pads stay 0 forever)
    for (int p = l; p < (int)(sizeof(hl) / 4); p += 64) ((int*)hl)[p] = 0;

    const long long TTHH = (long long)TT * HH;
    float*       hbase = hid + (long long)blockIdx.x * MB * TTHH + (long long)m * TTHH;
    const float* xbase = xp  + (long long)blockIdx.x * MB * TTHH + (long long)m * TTHH;

    // xp prefetch registers for the current step (13 x float4 = 52 VGPR)
    float4 xq[NTL];
#pragma unroll
    for (int nt = 0; nt < NTL; ++nt) {
        const int j0 = 16 * nt + 4 * kq;
        xq[nt] = (j0 < HH) ? *(const float4*)(xbase + j0)
                           : make_float4(0.f, 0.f, 0.f, 0.f);
    }

    int cur = 0;
#pragma unroll 1
    for (int t = 0; t < TT; ++t) {
        // B-fragments: H^T slices (7 ds_read_b128, in-wave lgkm ordering)
        half8 bf[KST];
        const _Float16* hb = &hl[cur][m][0];
#pragma unroll
        for (int ks = 0; ks < KST; ++ks)
            bf[ks] = *(const half8*)(hb + 32 * ks + 8 * kq);

        float*       hrow = hbase + (long long)t * HH;
        const int    tn   = (t + 1 < TT) ? t + 1 : t;
        const float* xrow = xbase + (long long)tn * HH;

#pragma unroll
        for (int nt = 0; nt < NTL; ++nt) {
            // even/odd k chains (4+3 deep, independent across 13 tiles)
            f32x4 ae = (f32x4){0.f, 0.f, 0.f, 0.f};
            f32x4 ao = (f32x4){0.f, 0.f, 0.f, 0.f};
#pragma unroll
            for (int ks = 0; ks < KST; ks += 2)
                ae = __builtin_amdgcn_mfma_f32_16x16x32_f16(wf[nt][ks], bf[ks], ae, 0, 0, 0);
#pragma unroll
            for (int ks = 1; ks < KST; ks += 2)
                ao = __builtin_amdgcn_mfma_f32_16x16x32_f16(wf[nt][ks], bf[ks], ao, 0, 0, 0);

            const int j0 = 16 * nt + 4 * kq;
            if (j0 < HH) {
                const float h0 = fmaxf(ae[0] + ao[0] + xq[nt].x, 0.f);
                const float h1 = fmaxf(ae[1] + ao[1] + xq[nt].y, 0.f);
                const float h2 = fmaxf(ae[2] + ao[2] + xq[nt].z, 0.f);
                const float h3 = fmaxf(ae[3] + ao[3] + xq[nt].w, 0.f);
                *(float4*)(hrow + j0) = make_float4(h0, h1, h2, h3);   // fire-and-forget
                half4v pk = {(_Float16)h0, (_Float16)h1, (_Float16)h2, (_Float16)h3};
                *(half4v*)&hl[cur ^ 1][m][j0] = pk;                    // next-step input
                xq[nt] = *(const float4*)(xrow + j0);                  // prefetch t+1
            }
        }
        cur ^= 1;
    }
}

// ---------------------------------------------------------------------------
// Phase 3: o[r] = sum_j W_out[j]*h[r][j] + b_out. (unchanged)
// ---------------------------------------------------------------------------
__global__ __launch_bounds__(256) void rnn_out(
    const float* __restrict__ hid, const float* __restrict__ Wout,
    const float* __restrict__ bout, float* __restrict__ out)
{
    const int wave = threadIdx.x >> 6;
    const int lane = threadIdx.x & 63;

    float wv[4];
#pragma unroll
    for (int mi = 0; mi < 4; ++mi) {
        int idx = lane + 64 * mi;
        wv[mi] = (idx < HH) ? Wout[idx] : 0.f;
    }
    const float bo = bout[0];

    const long long rbase = (long long)blockIdx.x * 64;
#pragma unroll 1
    for (int rr = wave; rr < 64; rr += 4) {
        const float* hr = hid + (rbase + rr) * HH;
        float p = 0.f;
#pragma unroll
        for (int mi = 0; mi < 4; ++mi) {
            int idx = lane + 64 * mi;
            if (idx < HH) p += wv[mi] * hr[idx];
        }
#pragma unroll
        for (int off = 32; off; off >>= 1) p += __shfl_down(p, off, 64);
        if (lane == 0) out[rbase + rr] = p + bo;
    }
}

extern "C" void kernel_launch(void* const* d_in, const int* in_sizes, int n_in,
                              void* d_out, int out_size, void* d_ws, size_t ws_size,
                              hipStream_t stream)
{
    const float* x    = (const float*)d_in[0];  // [128,1024,100]
    const float* Wih  = (const float*)d_in[1];  // [200,100]
    const float* Whh  = (const float*)d_in[2];  // [200,200]
    const float* bih  = (const float*)d_in[3];  // [200]
    const float* bhh  = (const float*)d_in[4];  // [200]
    const float* Wout = (const float*)d_in[5];  // [1,200]
    const float* bout = (const float*)d_in[6];  // [1]

    float* out = (float*)d_out;                 // [128*1024] outputs first
    float* hid = out + (long long)BB * TT;      // [128*1024*200] hiddens

    const size_t xp_bytes = (size_t)BB * TT * HH * sizeof(float);
    const bool use_ws = (ws_size >= xp_bytes);
    float* xparr = use_ws ? (float*)d_ws : hid;

    rnn_xproj<<<(BB * TT) / 128, 256, 0, stream>>>(x, Wih, bih, bhh, xparr);
    if (use_ws)
        rnn_recur<true><<<BB / MB, 64, 0, stream>>>(Whh, xparr, hid);
    else
        rnn_recur<false><<<BB / MB, 64, 0, stream>>>(Whh, xparr, hid);
    rnn_out<<<(BB * TT) / 64, 256, 0, stream>>>(hid, Wout, bout, out);
}

// Round 9
// 1910.350 us; speedup vs baseline: 2.1683x; 2.1683x over previous
//
#include <hip/hip_runtime.h>

#define BB 128
#define TT 1024
#define II 100
#define HH 200
#define MB 16          // batches per recurrence block -> 8 blocks
#define NTL 13         // ceil(200/16) j-tiles
#define KST 7          // ceil(200/32) k-steps
#define HSTR 232       // padded f16 row stride for H_lds (16B-aligned rows)

typedef _Float16 half8  __attribute__((ext_vector_type(8)));
typedef _Float16 half4v __attribute__((ext_vector_type(4)));
typedef float    f32x4  __attribute__((ext_vector_type(4)));

// ---------------------------------------------------------------------------
// Phase 1: xp[r][j] = b_ih[j] + b_hh[j] + sum_i x[r][i] * W_ih[j][i]
// Destination: d_ws (fast path) or hid (fallback).
// ---------------------------------------------------------------------------
__global__ __launch_bounds__(256, 1) void rnn_xproj(
    const float* __restrict__ x, const float* __restrict__ Wih,
    const float* __restrict__ bih, const float* __restrict__ bhh,
    float* __restrict__ xpdst)
{
    __shared__ __align__(16) float xs[128 * II];  // 51.2 KB
    const int tid = threadIdx.x;
    const int j = tid;
    const int jl = (j < HH) ? j : (HH - 1);

    float4 w[25];
    const float4* wrow = (const float4*)(Wih + jl * II);
#pragma unroll
    for (int kk = 0; kk < 25; ++kk) w[kk] = wrow[kk];
    const float bias = bih[jl] + bhh[jl];

    const long long r0 = (long long)blockIdx.x * 128;
    const float4* src = (const float4*)(x + r0 * II);
    float4* dst = (float4*)xs;
    for (int p = tid; p < 128 * II / 4; p += 256) dst[p] = src[p];
    __syncthreads();

    for (int row = 0; row < 128; ++row) {
        float a0 = 0.f, a1 = 0.f, a2 = 0.f, a3 = 0.f;
        const float4* xr = (const float4*)(xs + row * II);
#pragma unroll
        for (int kk = 0; kk < 25; ++kk) {
            float4 v = xr[kk];
            a0 += w[kk].x * v.x; a1 += w[kk].y * v.y;
            a2 += w[kk].z * v.z; a3 += w[kk].w * v.w;
        }
        if (j < HH)
            xpdst[(r0 + row) * HH + j] = bias + ((a0 + a1) + (a2 + a3));
    }
}

// ---------------------------------------------------------------------------
// Phase 2: MFMA recurrence — r5's 4-wave shape (validated resident: 28
// A-fragments/wave in AGPRs) with the three serializers removed:
//   1. xp stream in d_ws, h stream in hid (NoAlias via separate-storage)
//   2. xp prefetch loads issued BEFORE h stores (in-order vmcnt retirement:
//      waiting for a load never retires a later store, and no earlier one)
//   3. raw s_barrier + lgkmcnt(0)-only wait (memory-clobber sandwich, no
//      sched_barrier pin): global traffic stays in flight across steps.
// 8 blocks x 256 threads (4 waves, 1/SIMD). 2-step xp prefetch ping-pong.
// ---------------------------------------------------------------------------
template <bool WS>
__global__ __launch_bounds__(256, 1) __attribute__((amdgpu_waves_per_eu(1, 1)))
void rnn_recur(const float* __restrict__ Whh, const float* xp, float* hid)
{
#if __has_builtin(__builtin_assume_separate_storage)
    if constexpr (WS) __builtin_assume_separate_storage((void*)xp, (void*)hid);
#endif
    __shared__ _Float16 hl[2][MB][HSTR];   // 14.8 KB double-buffered H (fp16)

    const int tid = threadIdx.x;
    const int wv  = tid >> 6;
    const int l   = tid & 63;
    const int m   = l & 15;     // batch (B-col / C-col)
    const int kq  = l >> 4;     // k-subblock 0..3

    // ---- one-time: W_hh -> per-wave A-fragments (28 half8 -> AGPRs) ----
    half8 wf[4][KST];
#pragma unroll
    for (int i = 0; i < 4; ++i) {
        const int nt = 4 * i + wv;
        const bool v = (nt < NTL);
        int j = 16 * nt + m; if (j > HH - 1) j = HH - 1;
#pragma unroll
        for (int ks = 0; ks < KST; ++ks) {
            const int k0 = 32 * ks + 8 * kq;
            half8 f;
#pragma unroll
            for (int e = 0; e < 8; ++e) f[e] = (_Float16)0.f;
            if (v && k0 < HH) {
                const float4 lo = *(const float4*)(Whh + j * HH + k0);
                const float4 hi = *(const float4*)(Whh + j * HH + k0 + 4);
                f[0] = (_Float16)lo.x; f[1] = (_Float16)lo.y;
                f[2] = (_Float16)lo.z; f[3] = (_Float16)lo.w;
                f[4] = (_Float16)hi.x; f[5] = (_Float16)hi.y;
                f[6] = (_Float16)hi.z; f[7] = (_Float16)hi.w;
            }
            wf[i][ks] = f;
        }
    }

    // per-i epilogue geometry
    int  j0a[4]; bool stv[4];
#pragma unroll
    for (int i = 0; i < 4; ++i) {
        const int nt = 4 * i + wv;
        j0a[i] = 16 * nt + 4 * kq;
        stv[i] = (nt < NTL) && (j0a[i] < HH);
    }

    // zero both H buffers (incl. k-padding columns; pads stay 0 forever)
    {
        int* zp = (int*)hl;
        for (int p = tid; p < (int)(sizeof(hl) / 4); p += 256) zp[p] = 0;
    }
    __syncthreads();

    const long long TTHH = (long long)TT * HH;
    float*       hbase = hid + (long long)blockIdx.x * MB * TTHH + (long long)m * TTHH;
    const float* xbase = (WS ? xp : (const float*)hid)
                       + (long long)blockIdx.x * MB * TTHH + (long long)m * TTHH;

    // 2-step xp prefetch, statically indexed ping-pong (xq[e] holds xp(t), t%2==e)
    float4 xq[2][4];
#pragma unroll
    for (int e = 0; e < 2; ++e)
#pragma unroll
        for (int i = 0; i < 4; ++i)
            xq[e][i] = stv[i] ? *(const float4*)(xbase + (long long)e * HH + j0a[i])
                              : make_float4(0.f, 0.f, 0.f, 0.f);

    int cur = 0;
#pragma unroll 1
    for (int t2 = 0; t2 < TT; t2 += 2) {
#pragma unroll
        for (int e = 0; e < 2; ++e) {
            const int t = t2 + e;

            // B-fragments: H^T slices (7 ds_read_b128)
            half8 bf[KST];
            const _Float16* hb = &hl[cur][m][0];
#pragma unroll
            for (int ks = 0; ks < KST; ++ks)
                bf[ks] = *(const half8*)(hb + 32 * ks + 8 * kq);

            // MFMA accumulate, even/odd ks chains
            f32x4 accE[4], accO[4];
#pragma unroll
            for (int i = 0; i < 4; ++i) {
                accE[i] = (f32x4){0.f, 0.f, 0.f, 0.f};
                accO[i] = (f32x4){0.f, 0.f, 0.f, 0.f};
            }
#pragma unroll
            for (int ks = 0; ks < KST; ks += 2)
#pragma unroll
                for (int i = 0; i < 4; ++i)
                    accE[i] = __builtin_amdgcn_mfma_f32_16x16x32_f16(
                        wf[i][ks], bf[ks], accE[i], 0, 0, 0);
#pragma unroll
            for (int ks = 1; ks < KST; ks += 2)
#pragma unroll
                for (int i = 0; i < 4; ++i)
                    accO[i] = __builtin_amdgcn_mfma_f32_16x16x32_f16(
                        wf[i][ks], bf[ks], accO[i], 0, 0, 0);

            // epilogue: use xq[e] -> reload xq[e] for t+2 (LOAD BEFORE STORES)
            // -> ds_write next-H -> global h store (fire-and-forget)
            float*       hrow = hbase + (long long)t * HH;
            const int    tn   = (t + 2 < TT) ? t + 2 : t;   // clamped dead load at tail
            const float* xrow = xbase + (long long)tn * HH;
#pragma unroll
            for (int i = 0; i < 4; ++i) {
                if (!stv[i]) continue;
                const float h0 = fmaxf(accE[i][0] + accO[i][0] + xq[e][i].x, 0.f);
                const float h1 = fmaxf(accE[i][1] + accO[i][1] + xq[e][i].y, 0.f);
                const float h2 = fmaxf(accE[i][2] + accO[i][2] + xq[e][i].z, 0.f);
                const float h3 = fmaxf(accE[i][3] + accO[i][3] + xq[e][i].w, 0.f);
                xq[e][i] = *(const float4*)(xrow + j0a[i]);   // prefetch t+2
                half4v pk = {(_Float16)h0, (_Float16)h1, (_Float16)h2, (_Float16)h3};
                *(half4v*)&hl[cur ^ 1][m][j0a[i]] = pk;       // next-step input
                *(float4*)(hrow + j0a[i]) = make_float4(h0, h1, h2, h3);
            }

            // LDS-only fence + raw barrier; memory-clobber sandwich keeps
            // LDS ops ordered without pinning VALU/MFMA scheduling.
            asm volatile("s_waitcnt lgkmcnt(0)" ::: "memory");
            __builtin_amdgcn_s_barrier();
            asm volatile("" ::: "memory");
            cur ^= 1;
        }
    }
}

// ---------------------------------------------------------------------------
// Phase 3: o[r] = sum_j W_out[j]*h[r][j] + b_out. (unchanged)
// ---------------------------------------------------------------------------
__global__ __launch_bounds__(256) void rnn_out(
    const float* __restrict__ hid, const float* __restrict__ Wout,
    const float* __restrict__ bout, float* __restrict__ out)
{
    const int wave = threadIdx.x >> 6;
    const int lane = threadIdx.x & 63;

    float wv[4];
#pragma unroll
    for (int mi = 0; mi < 4; ++mi) {
        int idx = lane + 64 * mi;
        wv[mi] = (idx < HH) ? Wout[idx] : 0.f;
    }
    const float bo = bout[0];

    const long long rbase = (long long)blockIdx.x * 64;
#pragma unroll 1
    for (int rr = wave; rr < 64; rr += 4) {
        const float* hr = hid + (rbase + rr) * HH;
        float p = 0.f;
#pragma unroll
        for (int mi = 0; mi < 4; ++mi) {
            int idx = lane + 64 * mi;
            if (idx < HH) p += wv[mi] * hr[idx];
        }
#pragma unroll
        for (int off = 32; off; off >>= 1) p += __shfl_down(p, off, 64);
        if (lane == 0) out[rbase + rr] = p + bo;
    }
}

extern "C" void kernel_launch(void* const* d_in, const int* in_sizes, int n_in,
                              void* d_out, int out_size, void* d_ws, size_t ws_size,
                              hipStream_t stream)
{
    const float* x    = (const float*)d_in[0];  // [128,1024,100]
    const float* Wih  = (const float*)d_in[1];  // [200,100]
    const float* Whh  = (const float*)d_in[2];  // [200,200]
    const float* bih  = (const float*)d_in[3];  // [200]
    const float* bhh  = (const float*)d_in[4];  // [200]
    const float* Wout = (const float*)d_in[5];  // [1,200]
    const float* bout = (const float*)d_in[6];  // [1]

    float* out = (float*)d_out;                 // [128*1024] outputs first
    float* hid = out + (long long)BB * TT;      // [128*1024*200] hiddens

    const size_t xp_bytes = (size_t)BB * TT * HH * sizeof(float);
    const bool use_ws = (ws_size >= xp_bytes);
    float* xparr = use_ws ? (float*)d_ws : hid;

    rnn_xproj<<<(BB * TT) / 128, 256, 0, stream>>>(x, Wih, bih, bhh, xparr);
    if (use_ws)
        rnn_recur<true><<<BB / MB, 256, 0, stream>>>(Whh, xparr, hid);
    else
        rnn_recur<false><<<BB / MB, 256, 0, stream>>>(Whh, xparr, hid);
    rnn_out<<<(BB * TT) / 64, 256, 0, stream>>>(hid, Wout, bout, out);
}